// Round 11
// baseline (237.020 us; speedup 1.0000x reference)
//
#include <hip/hip_runtime.h>

#define FD 96
#define BSH 7       // 128 nodes per bucket
#define BNODES 128
#define NBLK 256    // blocks for 2D-histogram scatter

typedef float  f32x4 __attribute__((ext_vector_type(4)));
typedef short  s16x8 __attribute__((ext_vector_type(8)));

__device__ __forceinline__ unsigned short f2bf(float x) {
    unsigned u = __float_as_uint(x);
    u = (u + 0x7fffu + ((u >> 16) & 1u)) >> 16;
    return (unsigned short)u;
}
__device__ __forceinline__ float bflo(unsigned u) { return __uint_as_float(u << 16); }
__device__ __forceinline__ float bfhi(unsigned u) { return __uint_as_float(u & 0xffff0000u); }

__device__ __forceinline__ s16x8 pack8(const float t[8]) {
    union { unsigned u[4]; s16x8 v; } r;
    #pragma unroll
    for (int z = 0; z < 4; z++)
        r.u[z] = (unsigned)f2bf(t[2 * z]) | ((unsigned)f2bf(t[2 * z + 1]) << 16);
    return r.v;
}

#define ACC8(R, T) { \
    T[0] += bflo(R.x); T[1] += bfhi(R.x); \
    T[2] += bflo(R.y); T[3] += bfhi(R.y); \
    T[4] += bflo(R.z); T[5] += bfhi(R.z); \
    T[6] += bflo(R.w); T[7] += bfhi(R.w); }

#define FIN8(R, T, id) { \
    T[0] = fmaf(id, T[0], bflo(R.x)); T[1] = fmaf(id, T[1], bfhi(R.x)); \
    T[2] = fmaf(id, T[2], bflo(R.y)); T[3] = fmaf(id, T[3], bfhi(R.y)); \
    T[4] = fmaf(id, T[4], bflo(R.z)); T[5] = fmaf(id, T[5], bfhi(R.z)); \
    T[6] = fmaf(id, T[6], bflo(R.w)); T[7] = fmaf(id, T[7], bfhi(R.w)); }

// ---------------- bucketed CSR build (contention-free) ----------------

__global__ void k_h2d(const int* __restrict__ dst, int* __restrict__ hist2d,
                      int* __restrict__ bcnt, int E, int nbkt, int chunk) {
    __shared__ int hist[512];
    int tid = threadIdx.x, b = blockIdx.x;
    for (int i = tid; i < 512; i += 256) hist[i] = 0;
    __syncthreads();
    int lo = b * chunk, hi = min(lo + chunk, E);
    for (int i = lo + tid; i < hi; i += 256)
        atomicAdd(&hist[dst[i] >> BSH], 1);
    __syncthreads();
    for (int q = tid; q < nbkt; q += 256) {
        int hv = hist[q];
        hist2d[(size_t)q * NBLK + b] = hv;
        if (hv) atomicAdd(&bcnt[q], hv);
    }
}

__global__ void k_bscan(const int* __restrict__ bcnt, int* __restrict__ bbase, int nbkt) {
    __shared__ int sh[512];
    int tid = threadIdx.x;
    int v = (tid < nbkt) ? bcnt[tid] : 0;
    sh[tid] = v;
    __syncthreads();
    for (int off = 1; off < 512; off <<= 1) {
        int t = (tid >= off) ? sh[tid - off] : 0;
        __syncthreads();
        sh[tid] += t;
        __syncthreads();
    }
    int incl = sh[tid];
    if (tid < nbkt) bbase[tid] = incl - v;
    if (tid == nbkt - 1) bbase[nbkt] = incl;
}

__global__ void k_cscan(const int* __restrict__ hist2d, const int* __restrict__ bbase,
                        int* __restrict__ cursor2d) {
    __shared__ int sh[NBLK];
    int q = blockIdx.x, tid = threadIdx.x;
    int v = hist2d[(size_t)q * NBLK + tid];
    sh[tid] = v;
    __syncthreads();
    for (int off = 1; off < NBLK; off <<= 1) {
        int t = (tid >= off) ? sh[tid - off] : 0;
        __syncthreads();
        sh[tid] += t;
        __syncthreads();
    }
    cursor2d[(size_t)q * NBLK + tid] = bbase[q] + sh[tid] - v;
}

__global__ void k_scat(const int* __restrict__ src, const int* __restrict__ dst,
                       const int* __restrict__ cursor2d, uint2* __restrict__ ebuf,
                       int E, int nbkt, int chunk) {
    __shared__ int cur[512];
    int tid = threadIdx.x, b = blockIdx.x;
    for (int q = tid; q < nbkt; q += 256)
        cur[q] = cursor2d[(size_t)q * NBLK + b];
    __syncthreads();
    int lo = b * chunk, hi = min(lo + chunk, E);
    for (int i = lo + tid; i < hi; i += 256) {
        int d = dst[i];
        int p = atomicAdd(&cur[d >> BSH], 1);
        ebuf[p] = make_uint2((unsigned)d, (unsigned)src[i]);
    }
}

// per-bucket counting sort -> csr (orig src ids), perm-ordered rp2/re2/invd2, perm, inv_perm
__global__ void k_bsort(const uint2* __restrict__ ebuf, const int* __restrict__ bbase,
                        int* __restrict__ csr, int* __restrict__ rp2, int* __restrict__ re2,
                        float* __restrict__ invd2, int* __restrict__ perm,
                        int* __restrict__ inv_perm, int n) {
    __shared__ int cnt[BNODES];
    __shared__ int cur[BNODES];
    __shared__ int dh[64];
    const int b = blockIdx.x;
    const int tid = threadIdx.x;
    const int lo = bbase[b], hi = bbase[b + 1];
    if (tid < BNODES) cnt[tid] = 0;
    if (tid < 64) dh[tid] = 0;
    __syncthreads();
    for (int i = lo + tid; i < hi; i += blockDim.x)
        atomicAdd(&cnt[(int)ebuf[i].x - (b << BSH)], 1);
    __syncthreads();
    const int node = (b << BSH) + tid;
    const int v = (tid < BNODES) ? cnt[tid] : 0;
    const int dcl = min(v, 63);
    if (tid < BNODES && node < n) atomicAdd(&dh[dcl], 1);
    for (int off = 1; off < BNODES; off <<= 1) {
        int t = (tid < BNODES && tid >= off) ? cnt[tid - off] : 0;
        __syncthreads();
        if (tid < BNODES) cnt[tid] += t;
        __syncthreads();
    }
    int dv = (tid < 64) ? dh[tid] : 0;
    for (int off = 1; off < 64; off <<= 1) {
        int t = (tid < 64 && tid >= off) ? dh[tid - off] : 0;
        __syncthreads();
        if (tid < 64) dh[tid] += t;
        __syncthreads();
    }
    if (tid < 64) dh[tid] -= dv;
    __syncthreads();
    if (tid < BNODES) {
        int excl = cnt[tid] - v;
        if (node < n) {
            int rk = atomicAdd(&dh[dcl], 1);
            int slot = (b << BSH) + rk;
            perm[slot] = node;
            inv_perm[node] = slot;
            rp2[slot] = lo + excl;
            re2[slot] = lo + excl + v;
            invd2[slot] = (v > 0) ? (1.0f / (float)v) : 0.f;
        }
        cur[tid] = excl;
    }
    __syncthreads();
    for (int i = lo + tid; i < hi; i += blockDim.x) {
        uint2 e2 = ebuf[i];
        int local = (int)e2.x - (b << BSH);
        int p = lo + atomicAdd(&cur[local], 1);
        csr[p] = (int)e2.y;
    }
}

// translate csr original ids -> perm slots
__global__ void k_xlate(int* __restrict__ csr, const int* __restrict__ inv_perm, int E) {
    int i = blockIdx.x * blockDim.x + threadIdx.x;
    if (i < E) csr[i] = inv_perm[csr[i]];
}

// features fp32 (orig order) -> bf16 rows in perm order
__global__ void k_cvtp(const float* __restrict__ feat, const int* __restrict__ perm,
                       uint4* __restrict__ o, int n) {
    int g = blockIdx.x * blockDim.x + threadIdx.x;
    int i = g / 12;
    if (i >= n) return;
    int q = g - i * 12;
    int node = perm[i];
    const float4* row = (const float4*)(feat + (size_t)node * FD);
    float4 x = row[2 * q], y = row[2 * q + 1];
    uint4 r;
    r.x = (unsigned)f2bf(x.x) | ((unsigned)f2bf(x.y) << 16);
    r.y = (unsigned)f2bf(x.z) | ((unsigned)f2bf(x.w) << 16);
    r.z = (unsigned)f2bf(y.x) | ((unsigned)f2bf(y.y) << 16);
    r.w = (unsigned)f2bf(y.z) | ((unsigned)f2bf(y.w) << 16);
    o[g] = r;
}

// all three W (96x96 fp32 [k][f]) -> Wt bf16 [f][k], concatenated
__global__ void k_wprep3(const float* __restrict__ W1, const float* __restrict__ W2,
                         const float* __restrict__ W3, unsigned short* __restrict__ Wt) {
    int i = blockIdx.x * blockDim.x + threadIdx.x;
    if (i >= 3 * FD * FD) return;
    int m = i / (FD * FD), r = i - m * FD * FD;
    const float* W = (m == 0) ? W1 : ((m == 1) ? W2 : W3);
    int col = r % FD, k = r / FD;
    Wt[m * FD * FD + col * FD + k] = f2bf(W[r]);
}

// ---------------- fused layer: gather-mean + MFMA GEMM + bias + stats ----------------
// block 256 = 4 waves; wave owns 16 perm-rows. lane: r16=lane&15 (row), hg=lane>>4.
// Gather accumulates chunks {hg,4+hg,8+hg} (A-frag layout) in fp32, packs to bf16,
// 6 coltiles x 3 ksteps MFMA. OBF=1: coalesced bf16 y (perm order). OBF=0: fp32 scatter
// to original rows via perm.

template<int STATS, int OBF>
__global__ __launch_bounds__(256) void k_fused(
    const uint4* __restrict__ h,
    const int* __restrict__ rp2, const int* __restrict__ re2,
    const float* __restrict__ invd2, const int* __restrict__ csr2,
    const int* __restrict__ perm,
    const unsigned short* __restrict__ Wt, const float* __restrict__ bias,
    unsigned short* __restrict__ yb, float* __restrict__ yf,
    float* __restrict__ accg, int n)
{
    __shared__ float sred[2 * FD];
    const int tid = threadIdx.x, lane = tid & 63;
    const int r16 = lane & 15, hg = lane >> 4;
    const int tbase = blockIdx.x * 64 + (tid >> 6) * 16;
    const int idx = tbase + r16;

    float t0[8], t1[8], t2[8];
    #pragma unroll
    for (int z = 0; z < 8; z++) { t0[z] = 0.f; t1[z] = 0.f; t2[z] = 0.f; }

    if (idx < n) {
        int e = rp2[idx];
        const int end = re2[idx];
        for (; e + 4 <= end; e += 4) {
            int ca = csr2[e], cb = csr2[e + 1], cc = csr2[e + 2], cd = csr2[e + 3];
            uint4 A0 = h[(size_t)ca * 12 + hg], A1 = h[(size_t)ca * 12 + 4 + hg], A2 = h[(size_t)ca * 12 + 8 + hg];
            uint4 B0 = h[(size_t)cb * 12 + hg], B1 = h[(size_t)cb * 12 + 4 + hg], B2 = h[(size_t)cb * 12 + 8 + hg];
            uint4 C0 = h[(size_t)cc * 12 + hg], C1 = h[(size_t)cc * 12 + 4 + hg], C2 = h[(size_t)cc * 12 + 8 + hg];
            uint4 D0 = h[(size_t)cd * 12 + hg], D1 = h[(size_t)cd * 12 + 4 + hg], D2 = h[(size_t)cd * 12 + 8 + hg];
            ACC8(A0, t0); ACC8(A1, t1); ACC8(A2, t2);
            ACC8(B0, t0); ACC8(B1, t1); ACC8(B2, t2);
            ACC8(C0, t0); ACC8(C1, t1); ACC8(C2, t2);
            ACC8(D0, t0); ACC8(D1, t1); ACC8(D2, t2);
        }
        for (; e < end; e++) {
            int c = csr2[e];
            uint4 R0 = h[(size_t)c * 12 + hg], R1 = h[(size_t)c * 12 + 4 + hg], R2 = h[(size_t)c * 12 + 8 + hg];
            ACC8(R0, t0); ACC8(R1, t1); ACC8(R2, t2);
        }
        const float id = invd2[idx];
        uint4 S0 = h[(size_t)idx * 12 + hg], S1 = h[(size_t)idx * 12 + 4 + hg], S2 = h[(size_t)idx * 12 + 8 + hg];
        FIN8(S0, t0, id); FIN8(S1, t1, id); FIN8(S2, t2, id);
    }

    s16x8 a0 = pack8(t0), a1 = pack8(t1), a2 = pack8(t2);

    f32x4 acc[6];
    #pragma unroll
    for (int c2 = 0; c2 < 6; c2++) acc[c2] = (f32x4){0.f, 0.f, 0.f, 0.f};
    #pragma unroll
    for (int c2 = 0; c2 < 6; c2++) {
        const unsigned short* wp = Wt + (size_t)(c2 * 16 + r16) * FD + hg * 8;
        s16x8 b0 = *(const s16x8*)(wp);
        s16x8 b1 = *(const s16x8*)(wp + 32);
        s16x8 b2 = *(const s16x8*)(wp + 64);
        acc[c2] = __builtin_amdgcn_mfma_f32_16x16x32_bf16(a0, b0, acc[c2], 0, 0, 0);
        acc[c2] = __builtin_amdgcn_mfma_f32_16x16x32_bf16(a1, b1, acc[c2], 0, 0, 0);
        acc[c2] = __builtin_amdgcn_mfma_f32_16x16x32_bf16(a2, b2, acc[c2], 0, 0, 0);
    }

    int orow[4];
    #pragma unroll
    for (int j = 0; j < 4; j++) {
        int rr = tbase + hg * 4 + j;
        orow[j] = (!OBF && rr < n) ? perm[rr] : rr;
    }
    float s1v[6], s2v[6];
    #pragma unroll
    for (int c2 = 0; c2 < 6; c2++) { s1v[c2] = 0.f; s2v[c2] = 0.f; }
    #pragma unroll
    for (int c2 = 0; c2 < 6; c2++) {
        float bc = bias[c2 * 16 + r16];
        #pragma unroll
        for (int j = 0; j < 4; j++) {
            int rr = tbase + hg * 4 + j;
            if (rr < n) {
                float y = acc[c2][j] + bc;
                if (OBF) yb[(size_t)rr * FD + c2 * 16 + r16] = f2bf(y);
                else     yf[(size_t)orow[j] * FD + c2 * 16 + r16] = y;
                if (STATS) { s1v[c2] += y; s2v[c2] = fmaf(y, y, s2v[c2]); }
            }
        }
    }
    if (STATS) {
        if (tid < 2 * FD) sred[tid] = 0.f;
        __syncthreads();
        #pragma unroll
        for (int c2 = 0; c2 < 6; c2++) {
            float v1 = s1v[c2], v2 = s2v[c2];
            v1 += __shfl_xor(v1, 16, 64); v1 += __shfl_xor(v1, 32, 64);
            v2 += __shfl_xor(v2, 16, 64); v2 += __shfl_xor(v2, 32, 64);
            if (lane < 16) {
                atomicAdd(&sred[c2 * 16 + r16], v1);
                atomicAdd(&sred[FD + c2 * 16 + r16], v2);
            }
        }
        __syncthreads();
        if (tid < 2 * FD) atomicAdd(&accg[tid], sred[tid]);
    }
}

// BN constants: a = gamma*rsqrt(var+eps), c = beta - mu*a
__global__ void k_bnfin(const float* __restrict__ acc,
                        const float* __restrict__ gamma, const float* __restrict__ beta,
                        float* __restrict__ na, float* __restrict__ nc, float invN) {
    int f = threadIdx.x;
    float mu  = acc[f] * invN;
    float var = acc[FD + f] * invN - mu * mu;
    float a = gamma[f] * rsqrtf(var + 1e-5f);
    na[f] = a;
    nc[f] = beta[f] - mu * a;
}

// in-place y = relu(na*y + nc), bf16 rows
__global__ void k_norm(uint4* __restrict__ y, const float* __restrict__ na,
                       const float* __restrict__ nc, int n12) {
    int g = blockIdx.x * blockDim.x + threadIdx.x;
    if (g >= n12) return;
    int q = g % 12;
    float4 a0 = *(const float4*)(na + q * 8), a1 = *(const float4*)(na + q * 8 + 4);
    float4 c0 = *(const float4*)(nc + q * 8), c1 = *(const float4*)(nc + q * 8 + 4);
    uint4 r = y[g];
    float v0 = fmaxf(fmaf(a0.x, bflo(r.x), c0.x), 0.f);
    float v1 = fmaxf(fmaf(a0.y, bfhi(r.x), c0.y), 0.f);
    float v2 = fmaxf(fmaf(a0.z, bflo(r.y), c0.z), 0.f);
    float v3 = fmaxf(fmaf(a0.w, bfhi(r.y), c0.w), 0.f);
    float v4 = fmaxf(fmaf(a1.x, bflo(r.z), c1.x), 0.f);
    float v5 = fmaxf(fmaf(a1.y, bfhi(r.z), c1.y), 0.f);
    float v6 = fmaxf(fmaf(a1.z, bflo(r.w), c1.z), 0.f);
    float v7 = fmaxf(fmaf(a1.w, bfhi(r.w), c1.w), 0.f);
    uint4 pk;
    pk.x = (unsigned)f2bf(v0) | ((unsigned)f2bf(v1) << 16);
    pk.y = (unsigned)f2bf(v2) | ((unsigned)f2bf(v3) << 16);
    pk.z = (unsigned)f2bf(v4) | ((unsigned)f2bf(v5) << 16);
    pk.w = (unsigned)f2bf(v6) | ((unsigned)f2bf(v7) << 16);
    y[g] = pk;
}

extern "C" void kernel_launch(void* const* d_in, const int* in_sizes, int n_in,
                              void* d_out, int out_size, void* d_ws, size_t ws_size,
                              hipStream_t stream) {
    const float* feat = (const float*)d_in[0];
    const float* W1   = (const float*)d_in[1];
    const float* b1   = (const float*)d_in[2];
    const float* g1   = (const float*)d_in[3];
    const float* be1  = (const float*)d_in[4];
    const float* W2   = (const float*)d_in[5];
    const float* b2   = (const float*)d_in[6];
    const float* g2   = (const float*)d_in[7];
    const float* be2  = (const float*)d_in[8];
    const float* W3   = (const float*)d_in[9];
    const float* b3   = (const float*)d_in[10];
    const int*   src  = (const int*)d_in[11];
    const int*   dst  = (const int*)d_in[12];

    const int n = in_sizes[0] / FD;   // 50000
    const int e = in_sizes[11];       // 800000
    const int nbkt = (n + BNODES - 1) >> BSH;     // 391
    const int chunk = (e + NBLK - 1) / NBLK;      // 3125

    char* w = (char*)d_ws;
    unsigned short* hA  = (unsigned short*)w; w += (size_t)n * FD * 2;   // perm features / L2 out
    unsigned short* hB  = (unsigned short*)w; w += (size_t)n * FD * 2;   // L1 out (ebuf alias)
    unsigned short* Wt  = (unsigned short*)w; w += (size_t)3 * FD * FD * 2;
    int*   csr     = (int*)w;   w += (size_t)e * 4;
    int*   bcnt    = (int*)w;   w += 512 * 4;          // zeroed
    float* acc1    = (float*)w; w += 2 * FD * 4;       // zeroed
    float* acc2    = (float*)w; w += 2 * FD * 4;       // zeroed
    int*   bbase   = (int*)w;   w += 513 * 4;
    int*   hist2d  = (int*)w;   w += (size_t)512 * NBLK * 4;
    int*   cursor2d= (int*)w;   w += (size_t)512 * NBLK * 4;
    int*   rp2     = (int*)w;   w += (size_t)n * 4;
    int*   re2     = (int*)w;   w += (size_t)n * 4;
    float* invd2   = (float*)w; w += (size_t)n * 4;
    int*   perm    = (int*)w;   w += (size_t)n * 4;
    int*   invp    = (int*)w;   w += (size_t)n * 4;
    float* na1     = (float*)w; w += FD * 4;
    float* nc1     = (float*)w; w += FD * 4;
    float* na2     = (float*)w; w += FD * 4;
    float* nc2     = (float*)w; w += FD * 4;

    uint2* ebuf = (uint2*)hB;   // dead after k_bsort, before L1 writes hB

    float* O = (float*)d_out;
    const float invN = 1.0f / (float)n;
    const int FUSE_GRID = (n + 63) / 64;
    const int n12 = n * 12;

    hipMemsetAsync(bcnt, 0, (512 + 4 * FD) * 4, stream);
    k_h2d<<<NBLK, 256, 0, stream>>>(dst, hist2d, bcnt, e, nbkt, chunk);
    k_bscan<<<1, 512, 0, stream>>>(bcnt, bbase, nbkt);
    k_cscan<<<nbkt, NBLK, 0, stream>>>(hist2d, bbase, cursor2d);
    k_scat<<<NBLK, 256, 0, stream>>>(src, dst, cursor2d, ebuf, e, nbkt, chunk);
    k_bsort<<<nbkt, 256, 0, stream>>>(ebuf, bbase, csr, rp2, re2, invd2, perm, invp, n);
    k_xlate<<<(e + 255) / 256, 256, 0, stream>>>(csr, invp, e);
    k_cvtp<<<(n12 + 255) / 256, 256, 0, stream>>>(feat, perm, (uint4*)hA, n);
    k_wprep3<<<(3 * FD * FD + 255) / 256, 256, 0, stream>>>(W1, W2, W3, Wt);

    // layer 1: hA -> hB (bf16, perm order), stats
    k_fused<1, 1><<<FUSE_GRID, 256, 0, stream>>>((const uint4*)hA, rp2, re2, invd2, csr,
                                                 perm, Wt, b1, hB, nullptr, acc1, n);
    k_bnfin<<<1, FD, 0, stream>>>(acc1, g1, be1, na1, nc1, invN);
    k_norm<<<(n12 + 255) / 256, 256, 0, stream>>>((uint4*)hB, na1, nc1, n12);

    // layer 2: hB -> hA, stats
    k_fused<1, 1><<<FUSE_GRID, 256, 0, stream>>>((const uint4*)hB, rp2, re2, invd2, csr,
                                                 perm, Wt + FD * FD, b2, hA, nullptr, acc2, n);
    k_bnfin<<<1, FD, 0, stream>>>(acc2, g2, be2, na2, nc2, invN);
    k_norm<<<(n12 + 255) / 256, 256, 0, stream>>>((uint4*)hA, na2, nc2, n12);

    // layer 3: hA -> d_out fp32 (original row order via perm)
    k_fused<0, 0><<<FUSE_GRID, 256, 0, stream>>>((const uint4*)hA, rp2, re2, invd2, csr,
                                                 perm, Wt + 2 * FD * FD, b3, nullptr, O, nullptr, n);
}